// Round 12
// baseline (923.636 us; speedup 1.0000x reference)
//
#include <hip/hip_runtime.h>
#include <hip/hip_bf16.h>

// ---------------------------------------------------------------------------
// CNN_quantize round 12: quant v7 = single flat kernel, lane=(patch,k-slice),
// no LDS, no block barriers, 16-lane shuffle reduce for denom+argmin, plain
// float4 stores (4x256B contiguous per instr). Tests occupancy-limited-write
// hypothesis (32 waves/CU possible vs prior ~13).
// conv1 direct f32 -> bf16 NHWC; conv2/conv3 MFMA bf16; fc1/fc2 f32.
//
// Output layout (floats): [0,1280) pred; [1280] extra_loss;
// [1281,1281+84934656) att(3,221184,128); [84935937] contrastive.
//
// Workspace (byte offsets):
//   xq    f32  @ 0           14,155,776 B   (128,3,96,96)
//   y1    bf16 @ 14,155,776  69,337,088 B   (128,92,92,32) NHWC
//   y2    bf16 @ 83,492,864  15,859,712 B   (128,44,44,32) NHWC
//   y3    bf16 @ 99,352,576   1,638,400 B   (128,20,20,16) NHWC
//   y3f   f32  @ 100,990,976  3,276,800 B   (128,6400) NCHW flat
//   part  f32  @ 104,267,776  4,194,304 B
//   y4    f32  @ 108,462,080    262,144 B
//   wp2   bf16 @ 108,724,224     51,200 B
//   wp3   bf16 @ 108,775,424     25,600 B
//   cbn2  f32  @ 108,801,024      1,536 B
//   lossP f32  @ 108,802,560      1,024 B   256 partial sums
// ---------------------------------------------------------------------------

#define NP 221184

typedef __attribute__((ext_vector_type(8)))  short  short8;   // 8 bf16
typedef __attribute__((ext_vector_type(16))) float  f32x16;
typedef __attribute__((ext_vector_type(4)))  float  f32x4;

// ---------------------------------------------------------------------- quant
// Grid 13824 x 256. Wave = 4 patches; lane: pidx = lane>>4, kq = lane&15.
// Lane owns k rows {kq*4+j} and {64+kq*4+j}, j=0..3 (8 rows of 16).
// Denominator + argmin: 16-lane shfl_xor reduce (masks 1,2,4,8).
// att stores: 2 plain float4 per (lane,g); per instr 4 rows x 256B contiguous.
// xq: lane d=kq gathers cb[g][bi][d]; loss via 256-slot partial buffer.
__global__ __launch_bounds__(256) void quant_v7(
    const float* __restrict__ x, const float* __restrict__ cb,
    const float* __restrict__ cbn2,
    float* __restrict__ att, float* __restrict__ xq,
    float* __restrict__ lossPart)
{
  const int tid  = threadIdx.x;
  const int wv   = tid >> 6;
  const int lane = tid & 63;
  const int pidx = lane >> 4;
  const int kq   = lane & 15;
  const int n    = (blockIdx.x*4 + wv)*4 + pidx;   // exact: 13824*4*4 = 221184

  const float4* xp4 = (const float4*)(x + (size_t)n*16);
  float4 xa = xp4[0], xb = xp4[1], xc = xp4[2], xd = xp4[3];
  float xv[16] = {xa.x,xa.y,xa.z,xa.w, xb.x,xb.y,xb.z,xb.w,
                  xc.x,xc.y,xc.z,xc.w, xd.x,xd.y,xd.z,xd.w};
  const float xval = x[(size_t)n*16 + kq];   // this lane's (n, d=kq) element

  float xqacc = 0.f, lossLocal = 0.f;

#pragma unroll 1
  for (int g = 0; g < 3; ++g) {
    const float* cg  = cb + g*2048;
    const float* c2g = cbn2 + g*128;

    float e0[4], e1[4];
    float s = 0.f;
    float bm = 3.4e38f; int bi = 0;
#pragma unroll
    for (int j = 0; j < 4; ++j) {
      {
        const int k = kq*4 + j;
        const float4* cr = (const float4*)(cg + k*16);
        float4 c0 = cr[0], c1 = cr[1], c2 = cr[2], c3 = cr[3];
        float p0 = fmaf(xv[0],c0.x, fmaf(xv[1],c0.y, fmaf(xv[2],c0.z, xv[3]*c0.w)));
        float p1 = fmaf(xv[4],c1.x, fmaf(xv[5],c1.y, fmaf(xv[6],c1.z, xv[7]*c1.w)));
        float p2 = fmaf(xv[8],c2.x, fmaf(xv[9],c2.y, fmaf(xv[10],c2.z, xv[11]*c2.w)));
        float p3 = fmaf(xv[12],c3.x, fmaf(xv[13],c3.y, fmaf(xv[14],c3.z, xv[15]*c3.w)));
        float dot = (p0+p1)+(p2+p3);
        float t = fmaf(-2.f, dot, c2g[k]);       // = d2 - xn2
        float e = __expf(-t);
        e0[j] = e; s += e;
        if (t < bm || (t == bm && k < bi)) { bm = t; bi = k; }
      }
      {
        const int k = 64 + kq*4 + j;
        const float4* cr = (const float4*)(cg + k*16);
        float4 c0 = cr[0], c1 = cr[1], c2 = cr[2], c3 = cr[3];
        float p0 = fmaf(xv[0],c0.x, fmaf(xv[1],c0.y, fmaf(xv[2],c0.z, xv[3]*c0.w)));
        float p1 = fmaf(xv[4],c1.x, fmaf(xv[5],c1.y, fmaf(xv[6],c1.z, xv[7]*c1.w)));
        float p2 = fmaf(xv[8],c2.x, fmaf(xv[9],c2.y, fmaf(xv[10],c2.z, xv[11]*c2.w)));
        float p3 = fmaf(xv[12],c3.x, fmaf(xv[13],c3.y, fmaf(xv[14],c3.z, xv[15]*c3.w)));
        float dot = (p0+p1)+(p2+p3);
        float t = fmaf(-2.f, dot, c2g[k]);
        float e = __expf(-t);
        e1[j] = e; s += e;
        if (t < bm || (t == bm && k < bi)) { bm = t; bi = k; }
      }
    }

    // 16-lane group reduce (xor masks stay within the group)
#pragma unroll
    for (int off = 1; off < 16; off <<= 1) {
      s += __shfl_xor(s, off);
      float om = __shfl_xor(bm, off);
      int   oi = __shfl_xor(bi, off);
      if (om < bm || (om == bm && oi < bi)) { bm = om; bi = oi; }
    }
    float inv = 1.f / s;

    float* ab = att + ((size_t)g*NP + n)*128;
    float4 v0 = make_float4(e0[0]*inv, e0[1]*inv, e0[2]*inv, e0[3]*inv);
    float4 v1 = make_float4(e1[0]*inv, e1[1]*inv, e1[2]*inv, e1[3]*inv);
    *(float4*)(ab + kq*4)      = v0;   // lanes of a patch: 256B contiguous
    *(float4*)(ab + 64 + kq*4) = v1;

    // xq/loss: this lane's d = kq element of chosen code
    float q = cg[(size_t)bi*16 + kq];
    xqacc += q;
    float ee = q - xval;
    lossLocal += ee*ee;
  }

  xq[(size_t)n*16 + kq] = xqacc * (1.f/3.f);

#pragma unroll
  for (int off = 32; off > 0; off >>= 1) lossLocal += __shfl_xor(lossLocal, off);
  if (lane == 0) atomicAdd(&lossPart[blockIdx.x & 255], lossLocal);
}

// ----------------------------------------------------------------- weight pack
// wp2: [ks=50][lane=64][8 bf16]  k-order (ky,kx,ih); ic = ih*16 + (lane>>5)*8 + j
// wp3: [ks=25][lane=64][8 bf16]  k-order (ky,kx);    ic = (lane>>4)*8 + j
// cbn2: [3*128] = sum_d cb[g][k][d]^2
__global__ __launch_bounds__(256) void pack_w_kernel(
    const float* __restrict__ w2, const float* __restrict__ w3,
    const float* __restrict__ cb,
    __hip_bfloat16* __restrict__ p2, __hip_bfloat16* __restrict__ p3,
    float* __restrict__ cbn2)
{
  int t = blockIdx.x*256 + threadIdx.x;
  if (t < 25600) {
    int ks = t >> 9, l = (t >> 3) & 63, j = t & 7;
    int ky = ks/10, kx = (ks%10)>>1, ih = ks & 1;
    int oc = l & 31, kh = l >> 5;
    int ic = ih*16 + kh*8 + j;
    p2[t] = __float2bfloat16(w2[((oc*32 + ic)*5 + ky)*5 + kx]);
  }
  if (t < 12800) {
    int ks = t >> 9, l = (t >> 3) & 63, j = t & 7;
    int ky = ks/5, kx = ks%5;
    int oc = l & 15, kh = l >> 4;
    int ic = kh*8 + j;
    p3[t] = __float2bfloat16(w3[((oc*32 + ic)*5 + ky)*5 + kx]);
  }
  if (t < 384) {
    float s = 0.f;
#pragma unroll
    for (int d = 0; d < 16; ++d) { float v = cb[t*16 + d]; s += v*v; }
    cbn2[t] = s;
  }
}

// ---------------------------------------------------------------- conv1 direct
// (128,3,96,96) f32 NCHW -> (128,92,92,32) bf16 NHWC, relu.
__global__ __launch_bounds__(256) void conv1_kernel(
    const float* __restrict__ in, const float* __restrict__ wgt,
    const float* __restrict__ bias, __hip_bfloat16* __restrict__ out)
{
  int tile = blockIdx.x;
  int tx0 = (tile % 3) * 32, ty0 = (tile / 3) * 8;
  int ocg = blockIdx.y, n = blockIdx.z;

  int oc_l = threadIdx.x & 15;
  int slot = threadIdx.x >> 4;        // 0..15
  int rp = slot >> 2, cs = slot & 3;

  __shared__ __align__(16) float ins[3][12][36];
  __shared__ float wl[16][76];
  __shared__ __hip_bfloat16 tb[8][32][16];   // 8KB transpose buffer

  float acc[2][8];
#pragma unroll
  for (int r = 0; r < 2; ++r)
#pragma unroll
    for (int p = 0; p < 8; ++p) acc[r][p] = 0.f;

  for (int t = threadIdx.x; t < 3*12*36; t += 256) {
    int ic = t / (12*36); int r = t % (12*36); int ry = r / 36, rx = r % 36;
    int gy = ty0 + ry, gx = tx0 + rx;
    float v = 0.f;
    if (gy < 96 && gx < 96)
      v = in[(((size_t)n*3 + ic)*96 + gy)*96 + gx];
    ins[ic][ry][rx] = v;
  }
  for (int t = threadIdx.x; t < 16*75; t += 256) {
    int oc = t / 75, r = t % 75;
    wl[oc][r] = wgt[(size_t)(ocg*16 + oc)*75 + r];
  }
  __syncthreads();

#pragma unroll 1
  for (int ic = 0; ic < 3; ++ic) {
#pragma unroll
    for (int ky = 0; ky < 5; ++ky) {
      float wv[5];
#pragma unroll
      for (int kx = 0; kx < 5; ++kx) wv[kx] = wl[oc_l][ic*25 + ky*5 + kx];
#pragma unroll
      for (int rr = 0; rr < 2; ++rr) {
        int ry = 2*rp + rr + ky;
        const float4* rowp = (const float4*)&ins[ic][ry][cs*8];
        float4 a = rowp[0], b = rowp[1], c = rowp[2];
        float iv[12] = {a.x,a.y,a.z,a.w, b.x,b.y,b.z,b.w, c.x,c.y,c.z,c.w};
#pragma unroll
        for (int kx = 0; kx < 5; ++kx)
#pragma unroll
          for (int px = 0; px < 8; ++px)
            acc[rr][px] += iv[px + kx] * wv[kx];
      }
    }
  }
  __syncthreads();

  float bv = bias[ocg*16 + oc_l];
#pragma unroll
  for (int rr = 0; rr < 2; ++rr)
#pragma unroll
    for (int px = 0; px < 8; ++px)
      tb[2*rp + rr][cs*8 + px][oc_l] = __float2bfloat16(fmaxf(acc[rr][px] + bv, 0.f));
  __syncthreads();

  for (int t = threadIdx.x; t < 512; t += 256) {
    int byte = t * 16;
    int row = byte >> 10, col = (byte & 1023) >> 5, half = (byte >> 4) & 1;
    int gy = ty0 + row, gx = tx0 + col;
    if (gy < 92 && gx < 92) {
      *(int4*)((char*)out + ((((size_t)n*92 + gy)*92 + gx)*32 + ocg*16 + half*8)*2) =
          *(const int4*)((const char*)tb + byte);
    }
  }
}

// ------------------------------------------------------------------ conv2 MFMA
// (128,92,92,32) bf16 NHWC -> conv 5x5 (88x88) -> pool -> relu
//   -> (128,44,44,32) bf16 NHWC.
__global__ __launch_bounds__(384) void conv2_mfma(
    const __hip_bfloat16* __restrict__ in, const __hip_bfloat16* __restrict__ wp,
    const float* __restrict__ bias, __hip_bfloat16* __restrict__ out)
{
  __shared__ __align__(16) char lds[8*100*64];   // 51200 B

  int n = blockIdx.y, rg = blockIdx.x;
  int oy0 = rg * 4;
  int tid = threadIdx.x;

  for (int t = tid; t < 3200; t += 384) {
    int row = t / 400, rem = t % 400, px = rem >> 2, g = rem & 3;
    int4 v = make_int4(0,0,0,0);
    if (px < 92)
      v = *(const int4*)(in + (((size_t)n*92 + oy0 + row)*92 + px)*32 + g*8);
    int sb = ((row*100 + px) << 6) + ((g ^ ((px >> 1) & 3)) << 4);
    *(int4*)(lds + sb) = v;
  }
  __syncthreads();

  int wv = tid >> 6, lane = tid & 63;
  int rp = wv & 1, cg = wv >> 1;
  int col = lane & 31, khalf = lane >> 5;
  int ixb = cg*32 + col;

  f32x16 acc0, acc1;
#pragma unroll
  for (int i = 0; i < 16; ++i) { acc0[i] = 0.f; acc1[i] = 0.f; }

#pragma unroll
  for (int ks = 0; ks < 50; ++ks) {
    const int ky = ks/10, kx = (ks%10)>>1, ih = ks & 1;
    short8 av = *(const short8*)(wp + ks*512 + lane*8);
    int ix = ixb + kx;
    int g  = (ih*2 + khalf) ^ ((ix >> 1) & 3);
    {
      int row = 2*rp + 0 + ky;
      short8 bv = *(const short8*)(lds + ((row*100 + ix) << 6) + (g << 4));
      acc0 = __builtin_amdgcn_mfma_f32_32x32x16_bf16(av, bv, acc0, 0, 0, 0);
    }
    {
      int row = 2*rp + 1 + ky;
      short8 bv = *(const short8*)(lds + ((row*100 + ix) << 6) + (g << 4));
      acc1 = __builtin_amdgcn_mfma_f32_32x32x16_bf16(av, bv, acc1, 0, 0, 0);
    }
  }
  __syncthreads();

  {
#pragma unroll
    for (int rq = 0; rq < 4; ++rq) {
      __hip_bfloat16 pv[4];
#pragma unroll
      for (int rr = 0; rr < 4; ++rr) {
        int r = rq*4 + rr;
        float m = fmaxf(acc0[r], acc1[r]);
        float o = __shfl_xor(m, 1);
        float p = fmaxf(m, o);
        int oc = (r & 3) + 8*(r >> 2) + 4*khalf;
        pv[rr] = __float2bfloat16(fmaxf(p + bias[oc], 0.f));
      }
      if ((lane & 1) == 0) {
        int pl = col >> 1;
        *(uint2*)(lds + wv*1024 + pl*64 + (8*rq + 4*khalf)*2) = *(const uint2*)pv;
      }
    }
  }
  __syncthreads();

  if (tid < 384) {
    int byte = tid * 16;
    int w = byte >> 10, r = byte & 1023;
    int pl = r >> 6, ocq = (r & 63) >> 4;
    int pr = rg*2 + (w & 1);
    int pc = (w >> 1)*16 + pl;
    if (pc < 44) {
      *(int4*)(out + (((size_t)n*44 + pr)*44 + pc)*32 + ocq*8) =
          *(const int4*)(lds + byte);
    }
  }
}

// ------------------------------------------------------------------ conv3 MFMA
// (128,44,44,32) bf16 NHWC -> conv 5x5 (40x40) -> pool -> relu
//   -> (128,20,20,16) bf16 NHWC.
__global__ __launch_bounds__(384) void conv3_mfma(
    const __hip_bfloat16* __restrict__ in, const __hip_bfloat16* __restrict__ wp,
    const float* __restrict__ bias, __hip_bfloat16* __restrict__ out)
{
  __shared__ __align__(16) char lds[8*52*64];   // 26624 B

  int n = blockIdx.y, rg = blockIdx.x;
  int oy0 = rg * 4;
  int tid = threadIdx.x;

  for (int t = tid; t < 1664; t += 384) {
    int row = t / 208, rem = t % 208, px = rem >> 2, g = rem & 3;
    int4 v = make_int4(0,0,0,0);
    if (px < 44)
      v = *(const int4*)(in + (((size_t)n*44 + oy0 + row)*44 + px)*32 + g*8);
    int sb = ((row*52 + px) << 6) + ((g ^ ((px >> 1) & 3)) << 4);
    *(int4*)(lds + sb) = v;
  }
  __syncthreads();

  int wv = tid >> 6, lane = tid & 63;
  int rp = wv & 1, cg = wv >> 1;
  int col = lane & 15, kq = lane >> 4;
  int ixb = cg*16 + col;

  f32x4 acc0, acc1;
#pragma unroll
  for (int i = 0; i < 4; ++i) { acc0[i] = 0.f; acc1[i] = 0.f; }

#pragma unroll
  for (int ks = 0; ks < 25; ++ks) {
    const int ky = ks/5, kx = ks%5;
    short8 av = *(const short8*)(wp + ks*512 + lane*8);
    int ix = ixb + kx;
    int g  = kq ^ ((ix >> 1) & 3);
    {
      int row = 2*rp + 0 + ky;
      short8 bv = *(const short8*)(lds + ((row*52 + ix) << 6) + (g << 4));
      acc0 = __builtin_amdgcn_mfma_f32_16x16x32_bf16(av, bv, acc0, 0, 0, 0);
    }
    {
      int row = 2*rp + 1 + ky;
      short8 bv = *(const short8*)(lds + ((row*52 + ix) << 6) + (g << 4));
      acc1 = __builtin_amdgcn_mfma_f32_16x16x32_bf16(av, bv, acc1, 0, 0, 0);
    }
  }
  __syncthreads();

  {
    __hip_bfloat16 pv[4];
#pragma unroll
    for (int r = 0; r < 4; ++r) {
      float m = fmaxf(acc0[r], acc1[r]);
      float o = __shfl_xor(m, 1);
      float p = fmaxf(m, o);
      int oc = kq*4 + r;
      pv[r] = __float2bfloat16(fmaxf(p + bias[oc], 0.f));
    }
    if ((lane & 1) == 0) {
      int pl = col >> 1;
      *(uint2*)(lds + wv*256 + pl*32 + kq*8) = *(const uint2*)pv;
    }
  }
  __syncthreads();

  if (tid < 96) {
    int byte = tid * 16;
    int w = byte >> 8, r = byte & 255;
    int pl = r >> 5, half = (r & 31) >> 4;
    int pr = rg*2 + (w & 1);
    int pc = (w >> 1)*8 + pl;
    if (pc < 20) {
      *(int4*)(out + (((size_t)n*20 + pr)*20 + pc)*16 + half*8) =
          *(const int4*)(lds + byte);
    }
  }
}

// --------------------------------------------------------------------- repack
__global__ __launch_bounds__(256) void repack_y3(
    const __hip_bfloat16* __restrict__ y3, float* __restrict__ y3f)
{
  int t = blockIdx.x*256 + threadIdx.x;
  if (t < 819200) {
    int c = t & 15; int r = t >> 4;
    int x = r % 20; r /= 20;
    int y = r % 20; int m = r / 20;
    y3f[((size_t)m*16 + c)*400 + y*20 + x] = __bfloat162float(y3[t]);
  }
}

// ------------------------------------------------------------------------ fc1
__global__ __launch_bounds__(256) void fc1_partial(
    const float* __restrict__ x, const float* __restrict__ w,
    float* __restrict__ part)
{
  constexpr int KC = 6400 / 16;
  __shared__ float xl[128][16];
  __shared__ float wlds[32][17];
  int nt = blockIdx.x, ks = blockIdx.y;
  int k0 = ks * KC;
  int nl = threadIdx.x & 31;
  int mg = threadIdx.x >> 5;
  float acc[16];
#pragma unroll
  for (int j = 0; j < 16; ++j) acc[j] = 0.f;

  for (int kb = 0; kb < KC; kb += 16) {
    for (int t = threadIdx.x; t < 128*16; t += 256) {
      int m = t >> 4, kk = t & 15;
      xl[m][kk] = x[(size_t)m*6400 + k0 + kb + kk];
    }
    for (int t = threadIdx.x; t < 32*16; t += 256) {
      int nn = t >> 4, kk = t & 15;
      wlds[nn][kk] = w[(size_t)(nt*32 + nn)*6400 + k0 + kb + kk];
    }
    __syncthreads();
#pragma unroll
    for (int kk = 0; kk < 16; ++kk) {
      float wvv = wlds[nl][kk];
#pragma unroll
      for (int j = 0; j < 16; ++j)
        acc[j] += xl[mg + 8*j][kk] * wvv;
    }
    __syncthreads();
  }
#pragma unroll
  for (int j = 0; j < 16; ++j) {
    int m = mg + 8*j;
    part[((size_t)ks*128 + m)*512 + nt*32 + nl] = acc[j];
  }
}

__global__ __launch_bounds__(256) void fc1_reduce(
    const float* __restrict__ part, const float* __restrict__ bias,
    float* __restrict__ y4)
{
  int o = blockIdx.x*256 + threadIdx.x;
  int nn = o & 511;
  float s = 0.f;
#pragma unroll
  for (int ks = 0; ks < 16; ++ks)
    s += part[(size_t)ks*65536 + o];
  y4[o] = fmaxf(s + bias[nn], 0.f);
}

// ------------------------------------------------------------------------ fc2
__global__ __launch_bounds__(256) void fc2_kernel(
    const float* __restrict__ y4, const float* __restrict__ w2,
    const float* __restrict__ b2, float* __restrict__ pred)
{
  int o = blockIdx.x*256 + threadIdx.x;
  if (o >= 1280) return;
  int m = o / 10, c = o % 10;
  float s = 0.f;
  const float* yr = y4 + (size_t)m*512;
  const float* wr = w2 + (size_t)c*512;
#pragma unroll 8
  for (int k = 0; k < 512; ++k) s += yr[k]*wr[k];
  pred[o] = s + b2[c];
}

// -------------------------------------------------------------------- epilogue
__global__ void finalize_kernel(const float* __restrict__ lossPart,
                                float* __restrict__ out)
{
  int lane = threadIdx.x;   // 64 threads
  float s = lossPart[lane] + lossPart[lane+64] + lossPart[lane+128] + lossPart[lane+192];
#pragma unroll
  for (int off = 32; off > 0; off >>= 1) s += __shfl_xor(s, off);
  if (lane == 0) {
    out[1280] = 2.f * s / 10616832.f;
    out[84935937] = 0.f;
  }
}

// ---------------------------------------------------------------------- launch
extern "C" void kernel_launch(void* const* d_in, const int* in_sizes, int n_in,
                              void* d_out, int out_size, void* d_ws, size_t ws_size,
                              hipStream_t stream)
{
  const float* x   = (const float*)d_in[0];
  const float* cb  = (const float*)d_in[1];
  const float* w1  = (const float*)d_in[2];
  const float* b1  = (const float*)d_in[3];
  const float* w2  = (const float*)d_in[4];
  const float* b2  = (const float*)d_in[5];
  const float* w3  = (const float*)d_in[6];
  const float* b3  = (const float*)d_in[7];
  const float* wf1 = (const float*)d_in[8];
  const float* bf1 = (const float*)d_in[9];
  const float* wf2 = (const float*)d_in[10];
  const float* bf2 = (const float*)d_in[11];

  float* out = (float*)d_out;
  char*  ws  = (char*)d_ws;

  float*          xq    = (float*)         (ws + 0);
  __hip_bfloat16* y1    = (__hip_bfloat16*)(ws + 14155776);
  __hip_bfloat16* y2    = (__hip_bfloat16*)(ws + 83492864);
  __hip_bfloat16* y3    = (__hip_bfloat16*)(ws + 99352576);
  float*          y3f   = (float*)         (ws + 100990976);
  float*          part  = (float*)         (ws + 104267776);
  float*          y4    = (float*)         (ws + 108462080);
  __hip_bfloat16* wp2   = (__hip_bfloat16*)(ws + 108724224);
  __hip_bfloat16* wp3   = (__hip_bfloat16*)(ws + 108775424);
  float*          cbn2  = (float*)         (ws + 108801024);
  float*          lossP = (float*)         (ws + 108802560);

  hipMemsetAsync(lossP, 0, 1024, stream);

  // pack first: quant needs cbn2, convs need wp2/wp3
  pack_w_kernel<<<100, 256, 0, stream>>>(w2, w3, cb, wp2, wp3, cbn2);

  // single flat quant: att + xq + loss partials
  quant_v7<<<13824, 256, 0, stream>>>(x, cb, cbn2, out + 1281, xq, lossP);

  conv1_kernel<<<dim3(36, 2, 128), 256, 0, stream>>>(xq, w1, b1, y1);
  conv2_mfma<<<dim3(22, 128), 384, 0, stream>>>(y1, wp2, b2, y2);
  conv3_mfma<<<dim3(10, 128), 384, 0, stream>>>(y2, wp3, b3, y3);

  repack_y3<<<3200, 256, 0, stream>>>(y3, y3f);

  fc1_partial<<<dim3(16, 16), 256, 0, stream>>>(y3f, wf1, part);
  fc1_reduce<<<256, 256, 0, stream>>>(part, bf1, y4);
  fc2_kernel<<<5, 256, 0, stream>>>(y4, wf2, bf2, out);

  finalize_kernel<<<1, 64, 0, stream>>>(lossP, out);
}

// Round 13
// 473.793 us; speedup vs baseline: 1.9495x; 1.9495x over previous
//
#include <hip/hip_runtime.h>
#include <hip/hip_bf16.h>

// ---------------------------------------------------------------------------
// CNN_quantize round 13: quant reverted to v5 (best measured, 229us).
// Tail changes: conv1 merged to one 512-thr block (stage input once, 32 oc),
// repack_y3 deleted (fc1 reads y3 bf16 NHWC via NHWC-packed bf16 weights).
// conv2/conv3 MFMA unchanged.
//
// Output layout (floats): [0,1280) pred; [1280] extra_loss;
// [1281,1281+84934656) att(3,221184,128); [84935937] contrastive.
//
// Workspace (byte offsets):
//   xq    f32  @ 0           14,155,776 B   (128,3,96,96)
//   y1    bf16 @ 14,155,776  69,337,088 B   (128,92,92,32) NHWC
//   y2    bf16 @ 83,492,864  15,859,712 B   (128,44,44,32) NHWC
//   y3    bf16 @ 99,352,576   1,638,400 B   (128,20,20,16) NHWC
//   part  f32  @ 104,267,776  4,194,304 B
//   y4    f32  @ 108,462,080    262,144 B
//   wp2   bf16 @ 108,724,224     51,200 B
//   wp3   bf16 @ 108,775,424     25,600 B
//   cbn2  f32  @ 108,801,024      1,536 B
//   loss  f32  @ 108,802,560          4 B
//   wf1p  bf16 @ 108,802,624   6,553,600 B  (512,6400) NHWC k-order
// ---------------------------------------------------------------------------

#define NP 221184

typedef __attribute__((ext_vector_type(8)))  short  short8;   // 8 bf16
typedef __attribute__((ext_vector_type(16))) float  f32x16;
typedef __attribute__((ext_vector_type(4)))  float  f32x4;

// ---------------------------------------------------------------------- quant
// v5 (round 9, measured 229us): grid 3456 x 256, k-split across 4 waves,
// exps in regs, block reduce, granule-XOR-swizzled b128 stage, NT float4
// stores.
__global__ __launch_bounds__(256) void quant_v5(
    const float* __restrict__ x, const float* __restrict__ cb,
    const float* __restrict__ cbn2,
    float* __restrict__ att, float* __restrict__ xq, float* __restrict__ lossAcc)
{
  __shared__ float stage[4][64][32];   // 32 KB granule-swizzled
  __shared__ float sred[4][64];
  __shared__ float mred[4][64];
  __shared__ int   ired[4][64];

  const int tid  = threadIdx.x;
  const int wv   = tid >> 6;
  const int lane = tid & 63;
  const int n0   = blockIdx.x * 64;
  const int n    = n0 + lane;
  const int l7   = lane & 7;

  const float4* xp4 = (const float4*)(x + (size_t)n*16);
  float4 xa = xp4[0], xb = xp4[1], xc = xp4[2], xd = xp4[3];
  float xv[16] = {xa.x,xa.y,xa.z,xa.w, xb.x,xb.y,xb.z,xb.w,
                  xc.x,xc.y,xc.z,xc.w, xd.x,xd.y,xd.z,xd.w};
  float xn2 = 0.f;
#pragma unroll
  for (int d = 0; d < 16; ++d) xn2 += xv[d]*xv[d];

  float xqacc[16];
#pragma unroll
  for (int d = 0; d < 16; ++d) xqacc[d] = 0.f;
  float lossLocal = 0.f;

#pragma unroll 1
  for (int g = 0; g < 3; ++g) {
    const float* cg  = cb + g*2048 + wv*512;
    const float* c2g = cbn2 + g*128 + wv*32;

    float ex[32];
    float s = 0.f;
    float mv = 3.4e38f; int mi = 0;
#pragma unroll
    for (int kk = 0; kk < 32; ++kk) {
      const float4* cr = (const float4*)(cg + kk*16);
      float4 c0 = cr[0], c1 = cr[1], c2 = cr[2], c3 = cr[3];
      float p0 = fmaf(xv[0],c0.x, fmaf(xv[1],c0.y, fmaf(xv[2],c0.z, xv[3]*c0.w)));
      float p1 = fmaf(xv[4],c1.x, fmaf(xv[5],c1.y, fmaf(xv[6],c1.z, xv[7]*c1.w)));
      float p2 = fmaf(xv[8],c2.x, fmaf(xv[9],c2.y, fmaf(xv[10],c2.z, xv[11]*c2.w)));
      float p3 = fmaf(xv[12],c3.x, fmaf(xv[13],c3.y, fmaf(xv[14],c3.z, xv[15]*c3.w)));
      float dot = (p0+p1)+(p2+p3);
      float d2 = xn2 - 2.f*dot + c2g[kk];
      float e = __expf(-d2);
      ex[kk] = e;
      s += e;
      if (d2 < mv) { mv = d2; mi = wv*32 + kk; }   // strict < -> lowest k
    }

    __syncthreads();
    sred[wv][lane] = s;
    mred[wv][lane] = mv;
    ired[wv][lane] = mi;
    __syncthreads();
    float stot = (sred[0][lane] + sred[1][lane]) + (sred[2][lane] + sred[3][lane]);
    float bm = mred[0][lane]; int bi = ired[0][lane];
#pragma unroll
    for (int w = 1; w < 4; ++w) {
      float m2 = mred[w][lane];
      int   i2 = ired[w][lane];
      if (m2 < bm) { bm = m2; bi = i2; }
    }
    float inv = 1.f / stot;

#pragma unroll
    for (int j = 0; j < 8; ++j) {
      f32x4 v;
      v[0] = ex[4*j]   * inv;
      v[1] = ex[4*j+1] * inv;
      v[2] = ex[4*j+2] * inv;
      v[3] = ex[4*j+3] * inv;
      *(f32x4*)&stage[wv][lane][((j ^ l7) << 2)] = v;
    }
    __builtin_amdgcn_wave_barrier();

    {
      const int pr = lane >> 3;
      const int pg = l7 ^ pr;
      float* ab = att + ((size_t)g*NP + n0)*128 + wv*32;
#pragma unroll
      for (int i = 0; i < 8; ++i) {
        int p = pr + 8*i;
        f32x4 v = *(const f32x4*)&stage[wv][p][pg << 2];
        __builtin_nontemporal_store(v, (f32x4*)(ab + (size_t)p*128 + (l7 << 2)));
      }
    }
    __builtin_amdgcn_wave_barrier();

    if (wv == 0) {
      const float4* qr = (const float4*)(cb + g*2048 + bi*16);
      float4 q0 = qr[0], q1 = qr[1], q2 = qr[2], q3 = qr[3];
      float qv[16] = {q0.x,q0.y,q0.z,q0.w, q1.x,q1.y,q1.z,q1.w,
                      q2.x,q2.y,q2.z,q2.w, q3.x,q3.y,q3.z,q3.w};
#pragma unroll
      for (int d = 0; d < 16; ++d) {
        xqacc[d] += qv[d];
        float e = qv[d] - xv[d];
        lossLocal += e*e;
      }
    }
  }

  if (wv == 0) {
    float4* xqo = (float4*)(xq + (size_t)n*16);
    const float third = 1.f/3.f;
    xqo[0] = make_float4(xqacc[0]*third, xqacc[1]*third, xqacc[2]*third, xqacc[3]*third);
    xqo[1] = make_float4(xqacc[4]*third, xqacc[5]*third, xqacc[6]*third, xqacc[7]*third);
    xqo[2] = make_float4(xqacc[8]*third, xqacc[9]*third, xqacc[10]*third, xqacc[11]*third);
    xqo[3] = make_float4(xqacc[12]*third, xqacc[13]*third, xqacc[14]*third, xqacc[15]*third);
#pragma unroll
    for (int off = 32; off > 0; off >>= 1) lossLocal += __shfl_xor(lossLocal, off);
    if (lane == 0) atomicAdd(lossAcc, lossLocal);
  }
}

// ----------------------------------------------------------------- weight pack
__global__ __launch_bounds__(256) void pack_w_kernel(
    const float* __restrict__ w2, const float* __restrict__ w3,
    const float* __restrict__ cb,
    __hip_bfloat16* __restrict__ p2, __hip_bfloat16* __restrict__ p3,
    float* __restrict__ cbn2)
{
  int t = blockIdx.x*256 + threadIdx.x;
  if (t < 25600) {
    int ks = t >> 9, l = (t >> 3) & 63, j = t & 7;
    int ky = ks/10, kx = (ks%10)>>1, ih = ks & 1;
    int oc = l & 31, kh = l >> 5;
    int ic = ih*16 + kh*8 + j;
    p2[t] = __float2bfloat16(w2[((oc*32 + ic)*5 + ky)*5 + kx]);
  }
  if (t < 12800) {
    int ks = t >> 9, l = (t >> 3) & 63, j = t & 7;
    int ky = ks/5, kx = ks%5;
    int oc = l & 15, kh = l >> 4;
    int ic = kh*8 + j;
    p3[t] = __float2bfloat16(w3[((oc*32 + ic)*5 + ky)*5 + kx]);
  }
  if (t < 384) {
    float s = 0.f;
#pragma unroll
    for (int d = 0; d < 16; ++d) { float v = cb[t*16 + d]; s += v*v; }
    cbn2[t] = s;
  }
}

// fc1 weights -> NHWC k-order bf16: k' = (y*20+x)*16 + c ; src k = c*400+y*20+x
__global__ __launch_bounds__(256) void pack_wf1(
    const float* __restrict__ wf1, __hip_bfloat16* __restrict__ p)
{
  int t = blockIdx.x*256 + threadIdx.x;
  if (t < 512*6400) {
    int nn = t / 6400, k = t % 6400;
    int c = k & 15, yx = k >> 4;
    p[t] = __float2bfloat16(wf1[(size_t)nn*6400 + c*400 + yx]);
  }
}

// ---------------------------------------------------------------- conv1 direct
// (128,3,96,96) f32 NCHW -> (128,92,92,32) bf16 NHWC, relu.
// One 512-thr block per tile: all 32 oc, input staged ONCE. grid (36, 128).
__global__ __launch_bounds__(512) void conv1_kernel(
    const float* __restrict__ in, const float* __restrict__ wgt,
    const float* __restrict__ bias, __hip_bfloat16* __restrict__ out)
{
  int tile = blockIdx.x;
  int tx0 = (tile % 3) * 32, ty0 = (tile / 3) * 8;
  int n = blockIdx.y;

  int oc_l = threadIdx.x & 31;
  int slot = threadIdx.x >> 5;        // 0..15
  int rp = slot >> 2, cs = slot & 3;

  __shared__ __align__(16) float ins[3][12][36];   // 5184 B
  __shared__ float wl[32][77];                      // 9856 B, pad 77: no conflict
  __shared__ __hip_bfloat16 tb[8][32][32];          // 16384 B transpose buffer

  float acc[2][8];
#pragma unroll
  for (int r = 0; r < 2; ++r)
#pragma unroll
    for (int p = 0; p < 8; ++p) acc[r][p] = 0.f;

  for (int t = threadIdx.x; t < 3*12*36; t += 512) {
    int ic = t / (12*36); int r = t % (12*36); int ry = r / 36, rx = r % 36;
    int gy = ty0 + ry, gx = tx0 + rx;
    float v = 0.f;
    if (gy < 96 && gx < 96)
      v = in[(((size_t)n*3 + ic)*96 + gy)*96 + gx];
    ins[ic][ry][rx] = v;
  }
  for (int t = threadIdx.x; t < 32*75; t += 512) {
    int oc = t / 75, r = t % 75;
    wl[oc][r] = wgt[(size_t)oc*75 + r];
  }
  __syncthreads();

#pragma unroll 1
  for (int ic = 0; ic < 3; ++ic) {
#pragma unroll
    for (int ky = 0; ky < 5; ++ky) {
      float wv[5];
#pragma unroll
      for (int kx = 0; kx < 5; ++kx) wv[kx] = wl[oc_l][ic*25 + ky*5 + kx];
#pragma unroll
      for (int rr = 0; rr < 2; ++rr) {
        int ry = 2*rp + rr + ky;
        const float4* rowp = (const float4*)&ins[ic][ry][cs*8];
        float4 a = rowp[0], b = rowp[1], c = rowp[2];
        float iv[12] = {a.x,a.y,a.z,a.w, b.x,b.y,b.z,b.w, c.x,c.y,c.z,c.w};
#pragma unroll
        for (int kx = 0; kx < 5; ++kx)
#pragma unroll
          for (int px = 0; px < 8; ++px)
            acc[rr][px] += iv[px + kx] * wv[kx];
      }
    }
  }
  __syncthreads();

  float bv = bias[oc_l];
#pragma unroll
  for (int rr = 0; rr < 2; ++rr)
#pragma unroll
    for (int px = 0; px < 8; ++px)
      tb[2*rp + rr][cs*8 + px][oc_l] = __float2bfloat16(fmaxf(acc[rr][px] + bv, 0.f));
  __syncthreads();

  // store: tb row = 32px x 32oc x 2B = 2048B = 128 int4
  for (int t = threadIdx.x; t < 1024; t += 512) {
    int row = t >> 7, rem = t & 127, col = rem >> 2, q = rem & 3;
    int gy = ty0 + row, gx = tx0 + col;
    if (gy < 92 && gx < 92) {
      *(int4*)((char*)out + (((size_t)((n*92 + gy)*92 + gx))*32 + q*8)*2) =
          *(const int4*)((const char*)tb + t*16);
    }
  }
}

// ------------------------------------------------------------------ conv2 MFMA
__global__ __launch_bounds__(384) void conv2_mfma(
    const __hip_bfloat16* __restrict__ in, const __hip_bfloat16* __restrict__ wp,
    const float* __restrict__ bias, __hip_bfloat16* __restrict__ out)
{
  __shared__ __align__(16) char lds[8*100*64];   // 51200 B

  int n = blockIdx.y, rg = blockIdx.x;
  int oy0 = rg * 4;
  int tid = threadIdx.x;

  for (int t = tid; t < 3200; t += 384) {
    int row = t / 400, rem = t % 400, px = rem >> 2, g = rem & 3;
    int4 v = make_int4(0,0,0,0);
    if (px < 92)
      v = *(const int4*)(in + (((size_t)n*92 + oy0 + row)*92 + px)*32 + g*8);
    int sb = ((row*100 + px) << 6) + ((g ^ ((px >> 1) & 3)) << 4);
    *(int4*)(lds + sb) = v;
  }
  __syncthreads();

  int wv = tid >> 6, lane = tid & 63;
  int rp = wv & 1, cg = wv >> 1;
  int col = lane & 31, khalf = lane >> 5;
  int ixb = cg*32 + col;

  f32x16 acc0, acc1;
#pragma unroll
  for (int i = 0; i < 16; ++i) { acc0[i] = 0.f; acc1[i] = 0.f; }

#pragma unroll
  for (int ks = 0; ks < 50; ++ks) {
    const int ky = ks/10, kx = (ks%10)>>1, ih = ks & 1;
    short8 av = *(const short8*)(wp + ks*512 + lane*8);
    int ix = ixb + kx;
    int g  = (ih*2 + khalf) ^ ((ix >> 1) & 3);
    {
      int row = 2*rp + 0 + ky;
      short8 bv = *(const short8*)(lds + ((row*100 + ix) << 6) + (g << 4));
      acc0 = __builtin_amdgcn_mfma_f32_32x32x16_bf16(av, bv, acc0, 0, 0, 0);
    }
    {
      int row = 2*rp + 1 + ky;
      short8 bv = *(const short8*)(lds + ((row*100 + ix) << 6) + (g << 4));
      acc1 = __builtin_amdgcn_mfma_f32_32x32x16_bf16(av, bv, acc1, 0, 0, 0);
    }
  }
  __syncthreads();

  {
#pragma unroll
    for (int rq = 0; rq < 4; ++rq) {
      __hip_bfloat16 pv[4];
#pragma unroll
      for (int rr = 0; rr < 4; ++rr) {
        int r = rq*4 + rr;
        float m = fmaxf(acc0[r], acc1[r]);
        float o = __shfl_xor(m, 1);
        float p = fmaxf(m, o);
        int oc = (r & 3) + 8*(r >> 2) + 4*khalf;
        pv[rr] = __float2bfloat16(fmaxf(p + bias[oc], 0.f));
      }
      if ((lane & 1) == 0) {
        int pl = col >> 1;
        *(uint2*)(lds + wv*1024 + pl*64 + (8*rq + 4*khalf)*2) = *(const uint2*)pv;
      }
    }
  }
  __syncthreads();

  if (tid < 384) {
    int byte = tid * 16;
    int w = byte >> 10, r = byte & 1023;
    int pl = r >> 6, ocq = (r & 63) >> 4;
    int pr = rg*2 + (w & 1);
    int pc = (w >> 1)*16 + pl;
    if (pc < 44) {
      *(int4*)(out + (((size_t)n*44 + pr)*44 + pc)*32 + ocq*8) =
          *(const int4*)(lds + byte);
    }
  }
}

// ------------------------------------------------------------------ conv3 MFMA
__global__ __launch_bounds__(384) void conv3_mfma(
    const __hip_bfloat16* __restrict__ in, const __hip_bfloat16* __restrict__ wp,
    const float* __restrict__ bias, __hip_bfloat16* __restrict__ out)
{
  __shared__ __align__(16) char lds[8*52*64];   // 26624 B

  int n = blockIdx.y, rg = blockIdx.x;
  int oy0 = rg * 4;
  int tid = threadIdx.x;

  for (int t = tid; t < 1664; t += 384) {
    int row = t / 208, rem = t % 208, px = rem >> 2, g = rem & 3;
    int4 v = make_int4(0,0,0,0);
    if (px < 44)
      v = *(const int4*)(in + (((size_t)n*44 + oy0 + row)*44 + px)*32 + g*8);
    int sb = ((row*52 + px) << 6) + ((g ^ ((px >> 1) & 3)) << 4);
    *(int4*)(lds + sb) = v;
  }
  __syncthreads();

  int wv = tid >> 6, lane = tid & 63;
  int rp = wv & 1, cg = wv >> 1;
  int col = lane & 15, kq = lane >> 4;
  int ixb = cg*16 + col;

  f32x4 acc0, acc1;
#pragma unroll
  for (int i = 0; i < 4; ++i) { acc0[i] = 0.f; acc1[i] = 0.f; }

#pragma unroll
  for (int ks = 0; ks < 25; ++ks) {
    const int ky = ks/5, kx = ks%5;
    short8 av = *(const short8*)(wp + ks*512 + lane*8);
    int ix = ixb + kx;
    int g  = kq ^ ((ix >> 1) & 3);
    {
      int row = 2*rp + 0 + ky;
      short8 bv = *(const short8*)(lds + ((row*52 + ix) << 6) + (g << 4));
      acc0 = __builtin_amdgcn_mfma_f32_16x16x32_bf16(av, bv, acc0, 0, 0, 0);
    }
    {
      int row = 2*rp + 1 + ky;
      short8 bv = *(const short8*)(lds + ((row*52 + ix) << 6) + (g << 4));
      acc1 = __builtin_amdgcn_mfma_f32_16x16x32_bf16(av, bv, acc1, 0, 0, 0);
    }
  }
  __syncthreads();

  {
    __hip_bfloat16 pv[4];
#pragma unroll
    for (int r = 0; r < 4; ++r) {
      float m = fmaxf(acc0[r], acc1[r]);
      float o = __shfl_xor(m, 1);
      float p = fmaxf(m, o);
      int oc = kq*4 + r;
      pv[r] = __float2bfloat16(fmaxf(p + bias[oc], 0.f));
    }
    if ((lane & 1) == 0) {
      int pl = col >> 1;
      *(uint2*)(lds + wv*256 + pl*32 + kq*8) = *(const uint2*)pv;
    }
  }
  __syncthreads();

  if (tid < 96) {
    int byte = tid * 16;
    int w = byte >> 8, r = byte & 255;
    int pl = r >> 5, half = (r & 31) >> 4;
    int pr = rg*2 + (w & 1);
    int pc = (w >> 1)*8 + pl;
    if (pc < 20) {
      *(int4*)(out + (((size_t)n*20 + pr)*20 + pc)*16 + half*8) =
          *(const int4*)(lds + byte);
    }
  }
}

// ------------------------------------------------------------------------ fc1
// X = y3 bf16 NHWC (k' = (y*20+x)*16+c), W = wf1p bf16 same k-order.
__global__ __launch_bounds__(256) void fc1_partial(
    const __hip_bfloat16* __restrict__ x, const __hip_bfloat16* __restrict__ w,
    float* __restrict__ part)
{
  constexpr int KC = 6400 / 16;   // 400
  __shared__ float xl[128][16];
  __shared__ float wlds[32][17];
  int nt = blockIdx.x, ks = blockIdx.y;
  int k0 = ks * KC;
  int nl = threadIdx.x & 31;
  int mg = threadIdx.x >> 5;
  float acc[16];
#pragma unroll
  for (int j = 0; j < 16; ++j) acc[j] = 0.f;

  for (int kb = 0; kb < KC; kb += 16) {
    for (int t = threadIdx.x; t < 128*16; t += 256) {
      int m = t >> 4, kk = t & 15;
      xl[m][kk] = __bfloat162float(x[(size_t)m*6400 + k0 + kb + kk]);
    }
    for (int t = threadIdx.x; t < 32*16; t += 256) {
      int nn = t >> 4, kk = t & 15;
      wlds[nn][kk] = __bfloat162float(w[(size_t)(nt*32 + nn)*6400 + k0 + kb + kk]);
    }
    __syncthreads();
#pragma unroll
    for (int kk = 0; kk < 16; ++kk) {
      float wvv = wlds[nl][kk];
#pragma unroll
      for (int j = 0; j < 16; ++j)
        acc[j] += xl[mg + 8*j][kk] * wvv;
    }
    __syncthreads();
  }
#pragma unroll
  for (int j = 0; j < 16; ++j) {
    int m = mg + 8*j;
    part[((size_t)ks*128 + m)*512 + nt*32 + nl] = acc[j];
  }
}

__global__ __launch_bounds__(256) void fc1_reduce(
    const float* __restrict__ part, const float* __restrict__ bias,
    float* __restrict__ y4)
{
  int o = blockIdx.x*256 + threadIdx.x;
  int nn = o & 511;
  float s = 0.f;
#pragma unroll
  for (int ks = 0; ks < 16; ++ks)
    s += part[(size_t)ks*65536 + o];
  y4[o] = fmaxf(s + bias[nn], 0.f);
}

// ------------------------------------------------------------------------ fc2
__global__ __launch_bounds__(256) void fc2_kernel(
    const float* __restrict__ y4, const float* __restrict__ w2,
    const float* __restrict__ b2, float* __restrict__ pred)
{
  int o = blockIdx.x*256 + threadIdx.x;
  if (o >= 1280) return;
  int m = o / 10, c = o % 10;
  float s = 0.f;
  const float* yr = y4 + (size_t)m*512;
  const float* wr = w2 + (size_t)c*512;
#pragma unroll 8
  for (int k = 0; k < 512; ++k) s += yr[k]*wr[k];
  pred[o] = s + b2[c];
}

// -------------------------------------------------------------------- epilogue
__global__ void finalize_kernel(const float* __restrict__ lossAcc,
                                float* __restrict__ out)
{
  out[1280] = 2.f * (*lossAcc) / 10616832.f;
  out[84935937] = 0.f;
}

// ---------------------------------------------------------------------- launch
extern "C" void kernel_launch(void* const* d_in, const int* in_sizes, int n_in,
                              void* d_out, int out_size, void* d_ws, size_t ws_size,
                              hipStream_t stream)
{
  const float* x   = (const float*)d_in[0];
  const float* cb  = (const float*)d_in[1];
  const float* w1  = (const float*)d_in[2];
  const float* b1  = (const float*)d_in[3];
  const float* w2  = (const float*)d_in[4];
  const float* b2  = (const float*)d_in[5];
  const float* w3  = (const float*)d_in[6];
  const float* b3  = (const float*)d_in[7];
  const float* wf1 = (const float*)d_in[8];
  const float* bf1 = (const float*)d_in[9];
  const float* wf2 = (const float*)d_in[10];
  const float* bf2 = (const float*)d_in[11];

  float* out = (float*)d_out;
  char*  ws  = (char*)d_ws;

  float*          xq   = (float*)         (ws + 0);
  __hip_bfloat16* y1   = (__hip_bfloat16*)(ws + 14155776);
  __hip_bfloat16* y2   = (__hip_bfloat16*)(ws + 83492864);
  __hip_bfloat16* y3   = (__hip_bfloat16*)(ws + 99352576);
  float*          part = (float*)         (ws + 104267776);
  float*          y4   = (float*)         (ws + 108462080);
  __hip_bfloat16* wp2  = (__hip_bfloat16*)(ws + 108724224);
  __hip_bfloat16* wp3  = (__hip_bfloat16*)(ws + 108775424);
  float*          cbn2 = (float*)         (ws + 108801024);
  float*          loss = (float*)         (ws + 108802560);
  __hip_bfloat16* wf1p = (__hip_bfloat16*)(ws + 108802624);

  hipMemsetAsync(loss, 0, sizeof(float), stream);

  pack_w_kernel<<<100, 256, 0, stream>>>(w2, w3, cb, wp2, wp3, cbn2);
  pack_wf1<<<12800, 256, 0, stream>>>(wf1, wf1p);

  quant_v5<<<3456, 256, 0, stream>>>(x, cb, cbn2, out + 1281, xq, loss);

  conv1_kernel<<<dim3(36, 128), 512, 0, stream>>>(xq, w1, b1, y1);
  conv2_mfma<<<dim3(22, 128), 384, 0, stream>>>(y1, wp2, b2, y2);
  conv3_mfma<<<dim3(10, 128), 384, 0, stream>>>(y2, wp3, b3, y3);

  fc1_partial<<<dim3(16, 16), 256, 0, stream>>>(y3, wf1p, part);
  fc1_reduce<<<256, 256, 0, stream>>>(part, bf1, y4);
  fc2_kernel<<<5, 256, 0, stream>>>(y4, wf2, bf2, out);

  finalize_kernel<<<1, 1, 0, stream>>>(loss, out);
}